// Round 1
// baseline (120.029 us; speedup 1.0000x reference)
//
#include <hip/hip_runtime.h>

// MonotoneActivation: per (b,g) group of ARITY=4 inputs, sort-4, barycentric
// interpolation over the 2^4 lattice, OUT_DIM=4 outputs.
//
// R9 design = R8 (register-bitmask, nt stores) + FUSION + 16 rows/block.
//  - build_masks kernel eliminated: each thread rebuilds its own group's
//    64-bit lattice bitmask from params (256 B/thread, 16 KB table total,
//    L2-hot after the first blocks; ~150 VALU ops amortized over 16 rows).
//    Removes one dependent launch + serialization bubble from the graph.
//  - ROWS_PER_BLK 8 -> 16: 1024 blocks = 4 blocks/CU = 16 waves/CU, still
//    ample concurrency for a streaming kernel; halves per-row mask overhead
//    and redundant params reads.
//  - X loads stay normal (cached); out stores stay non-temporal (measured
//    best in R8). params is binary (0.0/1.0 exactly, corner 15 forced 1)
//    -> selection via (float)bit * coef is exact -> absmax 0.

#define GROUPS        256
#define ROWS_PER_BLK  16
#define BATCH         16384
#define NBLOCKS       (BATCH / ROWS_PER_BLK)   // 1024 = 4 blocks/CU
#define BLOCK_T       256

typedef float f4 __attribute__((ext_vector_type(4)));

__global__ __launch_bounds__(BLOCK_T, 4) void mono_act_fused(
    const float* __restrict__ X,
    const float* __restrict__ params,   // [256][16][4] f32, values in {0,1}
    float* __restrict__ out)            // [BATCH, GROUPS*4]
{
    const int g  = threadIdx.x;                    // group == lane column
    const int r0 = blockIdx.x * ROWS_PER_BLK;

    // ---- rebuild this group's 64-bit lattice bitmask (bit 4e+o = params[g][e][o]) ----
    const f4* __restrict__ P = reinterpret_cast<const f4*>(params) + (g << 4);
    unsigned long long m = 0ull;
    #pragma unroll
    for (int e = 0; e < 16; ++e) {
        const f4 p = P[e];
        const unsigned long long nib =
            (unsigned long long)(p.x != 0.0f)
          | ((unsigned long long)(p.y != 0.0f) << 1)
          | ((unsigned long long)(p.z != 0.0f) << 2)
          | ((unsigned long long)(p.w != 0.0f) << 3);
        m |= nib << (4 * e);
    }

    const f4* __restrict__ X4 = reinterpret_cast<const f4*>(X) + g;
    f4* __restrict__ O4       = reinterpret_cast<f4*>(out) + g;

    #pragma unroll
    for (int k = 0; k < ROWS_PER_BLK; ++k) {
        const size_t roff = (size_t)(r0 + k) * GROUPS;   // f4 units
        const f4 x = X4[roff];

        float a0 = x.x, a1 = x.y, a2 = x.z, a3 = x.w;
        int i0 = 1, i1 = 2, i2 = 4, i3 = 8;   // 1 << original index

        // stable sorting network (strict >): (0,1)(2,3)(0,2)(1,3)(1,2)
        // matches jnp.argsort stability; equal values give coef 0 so the
        // tie-broken corner choice cannot change the output anyway.
#define CEX(a, b, ia, ib)                                   \
        do {                                                \
            if (a > b) {                                    \
                float _t = a; a = b; b = _t;                \
                int _u = ia; ia = ib; ib = _u;              \
            }                                               \
        } while (0)
        CEX(a0, a1, i0, i1);
        CEX(a2, a3, i2, i3);
        CEX(a0, a2, i0, i2);
        CEX(a1, a3, i1, i3);
        CEX(a1, a2, i1, i2);
#undef CEX

        const float c0 = a0;
        const float c1 = a1 - a0;
        const float c2 = a2 - a1;
        const float c3 = a3 - a2;

        // reversed-cumsum lattice indices; e0==15 -> corner==1.0 (projected)
        const int e3 = i3;
        const int e2 = e3 | i2;
        const int e1 = e2 | i1;

        // selector nibbles: bit o of s_k = params[g][e_k][o]
        const unsigned int s1 = (unsigned int)(m >> (e1 << 2));
        const unsigned int s2 = (unsigned int)(m >> (e2 << 2));
        const unsigned int s3 = (unsigned int)(m >> (e3 << 2));

        f4 r;
        r.x = c0 + c1 * (float)( s1       & 1)
                 + c2 * (float)( s2       & 1)
                 + c3 * (float)( s3       & 1);
        r.y = c0 + c1 * (float)((s1 >> 1) & 1)
                 + c2 * (float)((s2 >> 1) & 1)
                 + c3 * (float)((s3 >> 1) & 1);
        r.z = c0 + c1 * (float)((s1 >> 2) & 1)
                 + c2 * (float)((s2 >> 2) & 1)
                 + c3 * (float)((s3 >> 2) & 1);
        r.w = c0 + c1 * (float)((s1 >> 3) & 1)
                 + c2 * (float)((s2 >> 3) & 1)
                 + c3 * (float)((s3 >> 3) & 1);

        __builtin_nontemporal_store(r, &O4[roff]);       // bypass caches on write
    }
}

extern "C" void kernel_launch(void* const* d_in, const int* in_sizes, int n_in,
                              void* d_out, int out_size, void* d_ws, size_t ws_size,
                              hipStream_t stream) {
    const float* X      = (const float*)d_in[0];
    const float* params = (const float*)d_in[1];
    float* out          = (float*)d_out;
    (void)d_ws; (void)ws_size;

    mono_act_fused<<<NBLOCKS, BLOCK_T, 0, stream>>>(X, params, out);
}